// Round 3
// baseline (2448.842 us; speedup 1.0000x reference)
//
#include <hip/hip_runtime.h>
#include <cstdint>

#define BB 16
#define DD 256
#define TT 2048
#define KK 8192
#define NN 32768            // BB*TT
#define QQ 8388608          // BB*DD*TT
typedef unsigned long long u64;

// order-preserving float->uint map (all our d values are positive, but keep general)
__device__ __forceinline__ unsigned mapf(float f) {
    unsigned u = __float_as_uint(f);
    return (u & 0x80000000u) ? ~u : (u | 0x80000000u);
}
__device__ __forceinline__ float unmapf(unsigned u) {
    return __uint_as_float((u & 0x80000000u) ? (u & 0x7FFFFFFFu) : ~u);
}

// ---------------------------------------------------------------------------
// Kernel 1: A32[n] = (float)(fp64 sum of z_n^2)  (only needed to +-few ulp:
// bucket boundaries don't depend on A's mantissa, only its binade/ulp offset)
// ---------------------------------------------------------------------------
__global__ __launch_bounds__(256) void k_prep(const float* __restrict__ z,
                                              float* __restrict__ A32,
                                              int* __restrict__ cnt,
                                              float* __restrict__ out) {
    int tid = threadIdx.x;
    int n   = blockIdx.x * 256 + tid;        // grid 128 -> [0,32768)
    if (n == 0) { *cnt = 0; out[QQ] = 0.0f; }
    int b = n >> 11, t = n & 2047;
    const float* zp = z + (size_t)b * (DD * TT) + t;
    double s = 0.0;
#pragma unroll 8
    for (int d = 0; d < DD; d++) {
        double v = (double)zp[(size_t)d * TT];
        s = fma(v, v, s);
    }
    A32[n] = (float)s;
}

// ---------------------------------------------------------------------------
// Kernel 2: fp32 GEMM phase, score = -2 z.e ; per row & k-half emit true top-2
// ---------------------------------------------------------------------------
__global__ __launch_bounds__(256) void k_argmin(const float* __restrict__ z,
                                                const float* __restrict__ emb,
                                                u64* __restrict__ cand2) {
    __shared__ __align__(16) float smem[8192];   // 32 KB
    float* As = smem;          // [32][128] d-major
    float* Bs = smem + 4096;   // [128][32] swizzled

    int tid = threadIdx.x;
    int tx  = tid & 15;
    int ty  = tid >> 4;
    int mt  = blockIdx.x;            // 0..255 row tile
    int kh  = blockIdx.y;            // 0..1   k half

    int bimg = mt >> 4;
    int t0   = (mt & 15) << 7;
    const float* zb = z + (size_t)bimg * (DD * TT) + t0;

    float bestv[8], bestv2[8];
    int   besti[8];
#pragma unroll
    for (int i = 0; i < 8; i++) { bestv[i] = 3.4e38f; bestv2[i] = 3.4e38f; besti[i] = 0; }

    int qa = tid & 31, ra = tid >> 5;
    int jb = tid >> 3, db = tid & 7;
    int swz_t = (tx & 7) << 2;

    for (int kc = 0; kc < 32; kc++) {
        int k0 = kh * 4096 + kc * 128;
        float acc[8][8];
#pragma unroll
        for (int i = 0; i < 8; i++)
#pragma unroll
            for (int j = 0; j < 8; j++) acc[i][j] = 0.0f;

        for (int dc = 0; dc < 8; dc++) {
            int d0 = dc * 32;
            __syncthreads();
#pragma unroll
            for (int s = 0; s < 4; s++) {
                int d = ra + 8 * s;
                float4 v = *(const float4*)(zb + (size_t)(d0 + d) * TT + 4 * qa);
                *(float4*)(As + d * 128 + 4 * qa) = v;
            }
#pragma unroll
            for (int s = 0; s < 4; s++) {
                int row = jb + 32 * s;
                float4 v = *(const float4*)(emb + (size_t)(k0 + row) * DD + d0 + 4 * db);
                int col  = (4 * db) ^ ((row & 7) << 2);
                *(float4*)(Bs + row * 32 + col) = v;
            }
            __syncthreads();
#pragma unroll
            for (int g = 0; g < 8; g++) {
                float4 bf[8];
#pragma unroll
                for (int in = 0; in < 8; in++) {
                    int n = in * 16 + tx;
                    bf[in] = *(const float4*)(Bs + n * 32 + ((4 * g) ^ swz_t));
                }
#pragma unroll
                for (int j = 0; j < 4; j++) {
                    int d = 4 * g + j;
                    float4 a0 = *(const float4*)(As + d * 128 + ty * 8);
                    float4 a1 = *(const float4*)(As + d * 128 + ty * 8 + 4);
                    float av[8] = {a0.x, a0.y, a0.z, a0.w, a1.x, a1.y, a1.z, a1.w};
#pragma unroll
                    for (int im = 0; im < 8; im++) {
#pragma unroll
                        for (int in = 0; in < 8; in++) {
                            const float* bfp = (const float*)&bf[in];
                            acc[im][in] = fmaf(av[im], bfp[j], acc[im][in]);
                        }
                    }
                }
            }
        }
        // per-thread top-2 (k ascending; strict < keeps lowest idx as winner)
#pragma unroll
        for (int in = 0; in < 8; in++) {
            int k = k0 + in * 16 + tx;
#pragma unroll
            for (int im = 0; im < 8; im++) {
                float s = -2.0f * acc[im][in];
                if (s < bestv[im]) {
                    bestv2[im] = bestv[im];
                    bestv[im]  = s; besti[im] = k;
                } else if (s < bestv2[im]) {
                    bestv2[im] = s;
                }
            }
        }
    }

    // row-level true top-2 across 16 tx threads
    __syncthreads();
    u64* red = (u64*)smem;                       // 128 rows x 16 thr x 2 = 32 KB
#pragma unroll
    for (int im = 0; im < 8; im++) {
        int r = ty * 8 + im;
        red[r * 32 + tx * 2 + 0] = ((u64)mapf(bestv[im]) << 32) | (unsigned)besti[im];
        red[r * 32 + tx * 2 + 1] = ((u64)mapf(bestv2[im]) << 32);
    }
    __syncthreads();
    if (tid < 128) {
        const u64* base = red + tid * 32;
        u64 p1 = base[0];
        u64 s2 = base[1];
        #pragma unroll
        for (int t = 1; t < 16; t++) {
            u64 c1 = base[t * 2], c2 = base[t * 2 + 1];
            if (c1 < p1) { s2 = (p1 < s2) ? p1 : s2; p1 = c1; }
            else         { s2 = (c1 < s2) ? c1 : s2; }
            s2 = (c2 < s2) ? c2 : s2;
        }
        int n = mt * 128 + tid;
        cand2[(size_t)n * 4 + kh * 2]     = p1;
        cand2[(size_t)n * 4 + kh * 2 + 1] = s2;
    }
}

// ---------------------------------------------------------------------------
// Kernel 3: merge halves; commit singleton-bucket rows, flag the rest
// ---------------------------------------------------------------------------
__global__ __launch_bounds__(256) void k_select(const u64* __restrict__ cand2,
                                                const float* __restrict__ A32,
                                                int* __restrict__ keys,
                                                int* __restrict__ cnt,
                                                int* __restrict__ list) {
    int n = blockIdx.x * 256 + threadIdx.x;      // grid 128
    u64 a1 = cand2[(size_t)n * 4 + 0], a2 = cand2[(size_t)n * 4 + 1];
    u64 b1 = cand2[(size_t)n * 4 + 2], b2 = cand2[(size_t)n * 4 + 3];
    u64 m1 = (a1 < b1) ? a1 : b1;
    u64 lo = (a1 < b1) ? b1 : a1;                // loser of the two winners
    u64 m2 = (a2 < b2) ? a2 : b2;
    m2 = (lo < m2) ? lo : m2;

    keys[n] = (int)(unsigned)(m1 & 0xFFFFFFFFull);
    float f1 = unmapf((unsigned)(m1 >> 32));
    float f2 = unmapf((unsigned)(m2 >> 32));
    // W = ulp(A) + generous phase-error slack; conservative near the 256 binade edge
    float W = (A32[n] >= 255.9f) ? 3.4e-5f : 1.8e-5f;
    if (f2 - f1 <= W) {
        int p = atomicAdd(cnt, 1);
        list[p] = n;
    }
}

// ---------------------------------------------------------------------------
// Kernel 4: exact reference emulation for flagged rows.
// d_k = fp32( A32 - 2*dot_k ), dot_k = sequential fp32 FMA chain d=0..255
// (BLAS GEBP microkernel order). argmin with lowest-index ties.
// 8 rows per block, 4 codes in flight per thread.
// ---------------------------------------------------------------------------
__global__ __launch_bounds__(256) void k_refine(const float* __restrict__ z,
                                                const float* __restrict__ emb,
                                                const float* __restrict__ A32,
                                                const int* __restrict__ list,
                                                const int* __restrict__ cnt,
                                                int* __restrict__ keys) {
    __shared__ __align__(16) float zs[256][8];   // [d][row] 8 KB
    __shared__ float aA[8];
    __shared__ int   ln[8];
    __shared__ u64   wred[4 * 8];

    int tid = threadIdx.x, lane = tid & 63, w = tid >> 6;
    int count = *cnt;
    int ngroups = (count + 7) >> 3;

    for (int g = blockIdx.x; g < ngroups; g += gridDim.x) {
        __syncthreads();
        // stage 8 rows of z (transposed) + metadata
#pragma unroll
        for (int r = 0; r < 8; r++) {
            int row = g * 8 + r;
            int n   = list[(row < count) ? row : 0];
            int b = n >> 11, t = n & 2047;
            zs[tid][r] = z[(size_t)b * (DD * TT) + (size_t)tid * TT + t];
            if (tid == 0) { ln[r] = (row < count) ? n : -1; aA[r] = A32[n]; }
        }
        __syncthreads();

        u64 best[8];
#pragma unroll
        for (int r = 0; r < 8; r++) best[r] = 0xFFFFFFFFFFFFFFFFull;

        float Ar[8];
#pragma unroll
        for (int r = 0; r < 8; r++) Ar[r] = aA[r];

        for (int c = 0; c < 8; c++) {           // 4 codes in flight x 8 iters
            int kbase = c * 1024 + tid;         // codes kbase + {0,256,512,768}
            const float4* e0 = (const float4*)(emb + (size_t)(kbase)       * DD);
            const float4* e1 = (const float4*)(emb + (size_t)(kbase + 256) * DD);
            const float4* e2 = (const float4*)(emb + (size_t)(kbase + 512) * DD);
            const float4* e3 = (const float4*)(emb + (size_t)(kbase + 768) * DD);
            float acc[4][8];
#pragma unroll
            for (int q = 0; q < 4; q++)
#pragma unroll
                for (int r = 0; r < 8; r++) acc[q][r] = 0.0f;

            for (int d4 = 0; d4 < 64; d4++) {
                float4 v0 = e0[d4], v1 = e1[d4], v2 = e2[d4], v3 = e3[d4];
                const float* p0 = (const float*)&v0;
                const float* p1 = (const float*)&v1;
                const float* p2 = (const float*)&v2;
                const float* p3 = (const float*)&v3;
#pragma unroll
                for (int i = 0; i < 4; i++) {
                    int d = 4 * d4 + i;
                    float4 za = *(const float4*)&zs[d][0];
                    float4 zb = *(const float4*)&zs[d][4];
                    const float* zr = (const float*)&za;
                    const float* zr2 = (const float*)&zb;
#pragma unroll
                    for (int r = 0; r < 4; r++) {
                        acc[0][r]     = fmaf(zr[r],  p0[i], acc[0][r]);
                        acc[1][r]     = fmaf(zr[r],  p1[i], acc[1][r]);
                        acc[2][r]     = fmaf(zr[r],  p2[i], acc[2][r]);
                        acc[3][r]     = fmaf(zr[r],  p3[i], acc[3][r]);
                        acc[0][r + 4] = fmaf(zr2[r], p0[i], acc[0][r + 4]);
                        acc[1][r + 4] = fmaf(zr2[r], p1[i], acc[1][r + 4]);
                        acc[2][r + 4] = fmaf(zr2[r], p2[i], acc[2][r + 4]);
                        acc[3][r + 4] = fmaf(zr2[r], p3[i], acc[3][r + 4]);
                    }
                }
            }
#pragma unroll
            for (int q = 0; q < 4; q++) {
                int k = kbase + q * 256;
#pragma unroll
                for (int r = 0; r < 8; r++) {
                    float dk = Ar[r] - 2.0f * acc[q][r];   // fp32, matches RN(A - x)
                    u64 p = ((u64)mapf(dk) << 32) | (unsigned)k;
                    best[r] = (p < best[r]) ? p : best[r];
                }
            }
        }
        // reduce across 256 threads per row (packed min: value, then lowest idx)
#pragma unroll
        for (int r = 0; r < 8; r++) {
            u64 v = best[r];
            for (int off = 32; off; off >>= 1) {
                u64 o = __shfl_down(v, off, 64);
                v = (o < v) ? o : v;
            }
            if (lane == 0) wred[w * 8 + r] = v;
        }
        __syncthreads();
        if (tid < 8) {
            u64 v = wred[tid];
#pragma unroll
            for (int j = 1; j < 4; j++) {
                u64 o = wred[j * 8 + tid];
                v = (o < v) ? o : v;
            }
            int n = ln[tid];
            if (n >= 0) keys[n] = (int)(unsigned)(v & 0xFFFFFFFFull);
        }
        __syncthreads();
    }
}

// ---------------------------------------------------------------------------
// Kernel 5: gather quantized, write outputs, loss = 1.25 * mean((q - z)^2)
// ---------------------------------------------------------------------------
__global__ __launch_bounds__(256) void k_out(const float* __restrict__ z,
                                             const float* __restrict__ emb,
                                             const int* __restrict__ keys,
                                             float* __restrict__ out) {
    int tid = threadIdx.x;
    int n   = blockIdx.x * 256 + tid;          // grid 128
    int b   = n >> 11;
    int t   = n & 2047;
    int idx = keys[n];
    out[QQ + 1 + n] = (float)idx;

    const float4* erow = (const float4*)(emb + (size_t)idx * DD);
    const float*  zp   = z   + (size_t)b * (DD * TT) + t;
    float*        op   = out + (size_t)b * (DD * TT) + t;

    float ssd = 0.0f;
#pragma unroll 4
    for (int d4 = 0; d4 < 64; d4++) {
        float4 q = erow[d4];
        float qa[4] = {q.x, q.y, q.z, q.w};
#pragma unroll
        for (int r = 0; r < 4; r++) {
            int d = 4 * d4 + r;
            float zv = zp[(size_t)d * TT];
            float df = qa[r] - zv;
            ssd = fmaf(df, df, ssd);
            op[(size_t)d * TT] = qa[r];
        }
    }
    for (int off = 32; off; off >>= 1) ssd += __shfl_down(ssd, off, 64);
    __shared__ float red[4];
    if ((tid & 63) == 0) red[tid >> 6] = ssd;
    __syncthreads();
    if (tid == 0) {
        float tot = red[0] + red[1] + red[2] + red[3];
        atomicAdd(out + QQ, tot * (1.25f / (float)QQ));
    }
}

// ---------------------------------------------------------------------------
extern "C" void kernel_launch(void* const* d_in, const int* in_sizes, int n_in,
                              void* d_out, int out_size, void* d_ws, size_t ws_size,
                              hipStream_t stream) {
    const float* z   = (const float*)d_in[0];   // [16, 256, 2048]
    const float* emb = (const float*)d_in[1];   // [8192, 256]
    float* out = (float*)d_out;                 // [Q quantized][1 loss][N idx]

    char* ws = (char*)d_ws;
    u64*   cand2 = (u64*)ws;                          // 1 MB   (32768*4*8)
    float* A32   = (float*)(ws + 1048576);            // 128 KB
    int*   keys  = (int*)(ws + 1048576 + 131072);     // 128 KB
    int*   list  = (int*)(ws + 1048576 + 262144);     // 128 KB
    int*   cnt   = (int*)(ws + 1048576 + 393216);     // 4 B

    k_prep  <<<128,          256, 0, stream>>>(z, A32, cnt, out);
    k_argmin<<<dim3(256, 2), 256, 0, stream>>>(z, emb, cand2);
    k_select<<<128,          256, 0, stream>>>(cand2, A32, keys, cnt, list);
    k_refine<<<256,          256, 0, stream>>>(z, emb, A32, list, cnt, keys);
    k_out   <<<128,          256, 0, stream>>>(z, emb, keys, out);
}

// Round 4
// 1331.969 us; speedup vs baseline: 1.8385x; 1.8385x over previous
//
#include <hip/hip_runtime.h>
#include <cstdint>

#define BB 16
#define DD 256
#define TT 2048
#define KK 8192
#define NN 32768            // BB*TT
#define QQ 8388608          // BB*DD*TT
typedef unsigned long long u64;

typedef __attribute__((ext_vector_type(8))) short short8;   // 8 bf16 (4 VGPRs)
typedef __attribute__((ext_vector_type(4))) float f32x4;    // MFMA C/D

#define GLOBAL_AS __attribute__((address_space(1)))
#define LDS_AS    __attribute__((address_space(3)))

// async global->LDS, 16 B per lane; LDS dest = wave-uniform base + lane*16
__device__ __forceinline__ void async_copy16(void* l, const void* g) {
    __builtin_amdgcn_global_load_lds((const GLOBAL_AS unsigned int*)g,
                                     (LDS_AS unsigned int*)l, 16, 0, 0);
}

__device__ __forceinline__ unsigned mapf(float f) {
    unsigned u = __float_as_uint(f);
    return (u & 0x80000000u) ? ~u : (u | 0x80000000u);
}
__device__ __forceinline__ float unmapf(unsigned u) {
    return __uint_as_float((u & 0x80000000u) ? (u & 0x7FFFFFFFu) : ~u);
}
__device__ __forceinline__ unsigned bf16_rne(float v) {
    unsigned ui = __float_as_uint(v);
    return (ui + 0x7FFFu + ((ui >> 16) & 1)) >> 16;
}

// ---------------------------------------------------------------------------
// A32[n] = fp32(fp64 sum of z_n^2); zero cnt & loss. grid 512 x 256
// ---------------------------------------------------------------------------
__global__ __launch_bounds__(256) void k_prepA(const float* __restrict__ z,
                                               float* __restrict__ A32,
                                               int* __restrict__ cnt,
                                               float* __restrict__ out) {
    __shared__ double sd[256];
    int tid = threadIdx.x;
    int r = tid & 63;               // row within block (coalesced over t)
    int c = tid >> 6;               // wave -> d quarter
    int n = blockIdx.x * 64 + r;
    if (blockIdx.x == 0 && tid == 0) { *cnt = 0; out[QQ] = 0.0f; }
    int b = n >> 11, t = n & 2047;
    const float* zp = z + (size_t)b * 524288 + t;
#pragma unroll 8
    for (int i = 0; i < 64; i++) {
        // accumulate per-quarter partial
        float v = zp[(size_t)(c * 64 + i) * 2048];
        sd[tid] = (i == 0) ? 0.0 : sd[tid];   // placeholder; real accum below
        (void)v;
        break;
    }
    double s = 0.0;
#pragma unroll 8
    for (int i = 0; i < 64; i++) {
        float v = zp[(size_t)(c * 64 + i) * 2048];
        s = fma((double)v, (double)v, s);
    }
    sd[tid] = s;
    __syncthreads();
    if (c == 0) {
        double tot = sd[r] + sd[64 + r] + sd[128 + r] + sd[192 + r];
        A32[n] = (float)tot;
    }
}

// ---------------------------------------------------------------------------
// z [b][d][t] fp32 -> zh/zl [n=b*2048+t][d] bf16 hi/lo. grid 2048 x 256
// ---------------------------------------------------------------------------
__global__ __launch_bounds__(256) void k_convZ(const float* __restrict__ z,
                                               unsigned short* __restrict__ zh,
                                               unsigned short* __restrict__ zl) {
    __shared__ float sm[64][65];
    int tid = threadIdx.x;
    int bid = blockIdx.x;
    int b  = bid >> 7;
    int dt = (bid >> 5) & 3;
    int tt = bid & 31;
    const float* zp = z + (size_t)b * 524288 + (size_t)dt * 64 * 2048 + tt * 64;
#pragma unroll
    for (int i = 0; i < 16; i++) {
        int idx = tid + 256 * i;
        int d = idx >> 6, t = idx & 63;
        sm[d][t] = zp[(size_t)d * 2048 + t];
    }
    __syncthreads();
    size_t rowbase = ((size_t)b * 2048 + (size_t)tt * 64) * 256 + dt * 64;
#pragma unroll
    for (int i = 0; i < 16; i++) {
        int idx = tid + 256 * i;
        int t = idx >> 6, d = idx & 63;
        float v = sm[d][t];
        unsigned hb = bf16_rne(v);
        float hf = __uint_as_float(hb << 16);
        unsigned lb = bf16_rne(v - hf);
        size_t o = rowbase + (size_t)t * 256 + d;
        zh[o] = (unsigned short)hb;
        zl[o] = (unsigned short)lb;
    }
}

// ---------------------------------------------------------------------------
// emb [k][d] fp32 -> eh/el bf16 hi/lo. grid 1024 x 256
// ---------------------------------------------------------------------------
__global__ __launch_bounds__(256) void k_convE(const float* __restrict__ emb,
                                               unsigned short* __restrict__ eh,
                                               unsigned short* __restrict__ el) {
    int base = (blockIdx.x * 256 + threadIdx.x) * 8;
    float4 v0 = *(const float4*)(emb + base);
    float4 v1 = *(const float4*)(emb + base + 4);
    float vv[8] = {v0.x, v0.y, v0.z, v0.w, v1.x, v1.y, v1.z, v1.w};
    short8 hv, lv;
#pragma unroll
    for (int i = 0; i < 8; i++) {
        unsigned hb = bf16_rne(vv[i]);
        float hf = __uint_as_float(hb << 16);
        unsigned lb = bf16_rne(vv[i] - hf);
        hv[i] = (short)hb;
        lv[i] = (short)lb;
    }
    *(short8*)(eh + base) = hv;
    *(short8*)(el + base) = lv;
}

// ---------------------------------------------------------------------------
// MFMA distance GEMM: score = -2*(zh.eh + zh.el + zl.eh)  (fp32 acc)
// Block: 128 rows x 1024 codes (8 slabs of 128). 4 waves of 32Mx128N.
// Emits per (row, code-group ng) the top-2 packed (score,idx).
// grid 2048 (mt = bid&255, ng = bid>>8)
// ---------------------------------------------------------------------------
__global__ __launch_bounds__(256, 3) void k_gemm(const unsigned short* __restrict__ zh,
                                                 const unsigned short* __restrict__ zl,
                                                 const unsigned short* __restrict__ eh,
                                                 const unsigned short* __restrict__ el,
                                                 u64* __restrict__ cand) {
    __shared__ __align__(16) unsigned short As[128 * 32];   // [row][k] 8 KB
    __shared__ __align__(16) unsigned short Bs[128 * 32];   // [code][k] 8 KB
    __shared__ u64 rtop[256];                               // 128 rows x 2

    int tid  = threadIdx.x;
    int w    = tid >> 6;            // wave id: rows w*32..w*32+31
    int lane = tid & 63;
    int lm   = lane & 15;
    int q    = lane >> 4;

    int bid = blockIdx.x;
    int mt  = bid & 255;
    int ng  = bid >> 8;             // 0..7 (code group of 1024)

    rtop[tid] = ~0ull;

    int srow  = lane >> 2;          // staging: row within 16-row group
    int spart = lane & 3;           // 16B chunk within 64B row-seg

    const unsigned short* Azh = zh + (size_t)mt * 128 * 256;
    const unsigned short* Azl = zl + (size_t)mt * 128 * 256;
    int r0 = w * 32;

    for (int ns = 0; ns < 8; ns++) {
        int n0 = ng * 1024 + ns * 128;
        f32x4 acc[2][8];
#pragma unroll
        for (int mi = 0; mi < 2; mi++)
#pragma unroll
            for (int ni = 0; ni < 8; ni++) acc[mi][ni] = (f32x4){0.f, 0.f, 0.f, 0.f};

        for (int ph = 0; ph < 3; ph++) {
            const unsigned short* Ap = (ph == 2) ? Azl : Azh;
            const unsigned short* Bp = ((ph == 1) ? el : eh) + (size_t)n0 * 256;
            for (int kc = 0; kc < 8; kc++) {
                __syncthreads();
                {
                    const unsigned short* g0 = Ap + (size_t)(r0 + srow) * 256 + kc * 32 + spart * 8;
                    async_copy16(&As[r0 * 32], g0);
                    const unsigned short* g1 = Ap + (size_t)(r0 + 16 + srow) * 256 + kc * 32 + spart * 8;
                    async_copy16(&As[(r0 + 16) * 32], g1);
                    const unsigned short* g2 = Bp + (size_t)(r0 + srow) * 256 + kc * 32 + spart * 8;
                    async_copy16(&Bs[r0 * 32], g2);
                    const unsigned short* g3 = Bp + (size_t)(r0 + 16 + srow) * 256 + kc * 32 + spart * 8;
                    async_copy16(&Bs[(r0 + 16) * 32], g3);
                }
                __syncthreads();
                short8 a0 = *(const short8*)&As[(r0 + lm) * 32 + q * 8];
                short8 a1 = *(const short8*)&As[(r0 + 16 + lm) * 32 + q * 8];
                short8 bfr[8];
#pragma unroll
                for (int ni = 0; ni < 8; ni++)
                    bfr[ni] = *(const short8*)&Bs[(ni * 16 + lm) * 32 + q * 8];
#pragma unroll
                for (int ni = 0; ni < 8; ni++) {
                    acc[0][ni] = __builtin_amdgcn_mfma_f32_16x16x32_bf16(a0, bfr[ni], acc[0][ni], 0, 0, 0);
                    acc[1][ni] = __builtin_amdgcn_mfma_f32_16x16x32_bf16(a1, bfr[ni], acc[1][ni], 0, 0, 0);
                }
            }
        }
        // per-slab top-2: in-lane over ni, butterfly over 16 lm-lanes
#pragma unroll
        for (int mi = 0; mi < 2; mi++)
#pragma unroll
            for (int reg = 0; reg < 4; reg++) {
                u64 p1 = ~0ull, p2 = ~0ull;
#pragma unroll
                for (int ni = 0; ni < 8; ni++) {
                    float sc = -2.0f * acc[mi][ni][reg];
                    unsigned code = (unsigned)(n0 + ni * 16 + lm);
                    u64 pk = ((u64)mapf(sc) << 32) | code;
                    if (pk < p1) { p2 = p1; p1 = pk; }
                    else if (pk < p2) { p2 = pk; }
                }
#pragma unroll
                for (int msk = 1; msk <= 8; msk <<= 1) {
                    u64 q1 = __shfl_xor(p1, msk, 64);
                    u64 q2 = __shfl_xor(p2, msk, 64);
                    u64 n1 = (p1 < q1) ? p1 : q1;
                    u64 hi = (p1 < q1) ? q1 : p1;
                    u64 n2 = (q2 < p2) ? q2 : p2;
                    n2 = (hi < n2) ? hi : n2;
                    p1 = n1; p2 = n2;
                }
                if (lm == 0) {
                    int m = w * 32 + mi * 16 + q * 4 + reg;   // exclusive owner
                    u64 r1 = rtop[m * 2], r2 = rtop[m * 2 + 1];
                    u64 n1 = (p1 < r1) ? p1 : r1;
                    u64 hi = (p1 < r1) ? r1 : p1;
                    u64 n2 = (p2 < r2) ? p2 : r2;
                    n2 = (hi < n2) ? hi : n2;
                    rtop[m * 2] = n1; rtop[m * 2 + 1] = n2;
                }
            }
    }
    __syncthreads();
    if (tid < 128) {
        size_t o = ((size_t)ng * 32768 + (size_t)mt * 128 + tid) * 2;
        cand[o]     = rtop[tid * 2];
        cand[o + 1] = rtop[tid * 2 + 1];
    }
}

// ---------------------------------------------------------------------------
// select (MFMA path): merge 8 (top1,top2) pairs; commit or flag. grid 128
// ---------------------------------------------------------------------------
__global__ __launch_bounds__(256) void k_select(const u64* __restrict__ cand,
                                                const float* __restrict__ A32,
                                                int* __restrict__ keys,
                                                int* __restrict__ cnt,
                                                int* __restrict__ list) {
    int n = blockIdx.x * 256 + threadIdx.x;
    u64 m1 = cand[(size_t)n * 2];
    u64 m2 = cand[(size_t)n * 2 + 1];
#pragma unroll
    for (int j = 1; j < 8; j++) {
        u64 c1 = cand[((size_t)j * 32768 + n) * 2];
        u64 c2 = cand[((size_t)j * 32768 + n) * 2 + 1];
        if (c1 < m1) { m2 = (m1 < m2) ? m1 : m2; m1 = c1; }
        else         { m2 = (c1 < m2) ? c1 : m2; }
        m2 = (c2 < m2) ? c2 : m2;
    }
    keys[n] = (int)(unsigned)(m1 & 0xFFFFFFFFull);
    float f1 = unmapf((unsigned)(m1 >> 32));
    float f2 = unmapf((unsigned)(m2 >> 32));
    float W = ((A32[n] >= 255.9f) ? 3.4e-5f : 1.8e-5f) + 4e-6f;  // + 2*eps(bf16x3)
    if (f2 - f1 <= W) {
        int p = atomicAdd(cnt, 1);
        list[p] = n;
    }
}

// ---------------------------------------------------------------------------
// FALLBACK path (round-3 proven): fp32 VALU GEMM argmin + its select
// ---------------------------------------------------------------------------
__global__ __launch_bounds__(256) void k_argmin_fb(const float* __restrict__ z,
                                                   const float* __restrict__ emb,
                                                   u64* __restrict__ cand2) {
    __shared__ __align__(16) float smem[8192];
    float* As = smem;
    float* Bs = smem + 4096;

    int tid = threadIdx.x;
    int tx  = tid & 15;
    int ty  = tid >> 4;
    int mt  = blockIdx.x;
    int kh  = blockIdx.y;

    int bimg = mt >> 4;
    int t0   = (mt & 15) << 7;
    const float* zb = z + (size_t)bimg * (DD * TT) + t0;

    float bestv[8], bestv2[8];
    int   besti[8];
#pragma unroll
    for (int i = 0; i < 8; i++) { bestv[i] = 3.4e38f; bestv2[i] = 3.4e38f; besti[i] = 0; }

    int qa = tid & 31, ra = tid >> 5;
    int jb = tid >> 3, db = tid & 7;
    int swz_t = (tx & 7) << 2;

    for (int kc = 0; kc < 32; kc++) {
        int k0 = kh * 4096 + kc * 128;
        float acc[8][8];
#pragma unroll
        for (int i = 0; i < 8; i++)
#pragma unroll
            for (int j = 0; j < 8; j++) acc[i][j] = 0.0f;

        for (int dc = 0; dc < 8; dc++) {
            int d0 = dc * 32;
            __syncthreads();
#pragma unroll
            for (int s = 0; s < 4; s++) {
                int d = ra + 8 * s;
                float4 v = *(const float4*)(zb + (size_t)(d0 + d) * TT + 4 * qa);
                *(float4*)(As + d * 128 + 4 * qa) = v;
            }
#pragma unroll
            for (int s = 0; s < 4; s++) {
                int row = jb + 32 * s;
                float4 v = *(const float4*)(emb + (size_t)(k0 + row) * DD + d0 + 4 * db);
                int col  = (4 * db) ^ ((row & 7) << 2);
                *(float4*)(Bs + row * 32 + col) = v;
            }
            __syncthreads();
#pragma unroll
            for (int g = 0; g < 8; g++) {
                float4 bf[8];
#pragma unroll
                for (int in = 0; in < 8; in++) {
                    int nn = in * 16 + tx;
                    bf[in] = *(const float4*)(Bs + nn * 32 + ((4 * g) ^ swz_t));
                }
#pragma unroll
                for (int j = 0; j < 4; j++) {
                    int d = 4 * g + j;
                    float4 a0 = *(const float4*)(As + d * 128 + ty * 8);
                    float4 a1 = *(const float4*)(As + d * 128 + ty * 8 + 4);
                    float av[8] = {a0.x, a0.y, a0.z, a0.w, a1.x, a1.y, a1.z, a1.w};
#pragma unroll
                    for (int im = 0; im < 8; im++) {
#pragma unroll
                        for (int in = 0; in < 8; in++) {
                            const float* bfp = (const float*)&bf[in];
                            acc[im][in] = fmaf(av[im], bfp[j], acc[im][in]);
                        }
                    }
                }
            }
        }
#pragma unroll
        for (int in = 0; in < 8; in++) {
            int k = k0 + in * 16 + tx;
#pragma unroll
            for (int im = 0; im < 8; im++) {
                float s = -2.0f * acc[im][in];
                if (s < bestv[im]) { bestv2[im] = bestv[im]; bestv[im] = s; besti[im] = k; }
                else if (s < bestv2[im]) { bestv2[im] = s; }
            }
        }
    }

    __syncthreads();
    u64* red = (u64*)smem;
#pragma unroll
    for (int im = 0; im < 8; im++) {
        int r = ty * 8 + im;
        red[r * 32 + tx * 2 + 0] = ((u64)mapf(bestv[im]) << 32) | (unsigned)besti[im];
        red[r * 32 + tx * 2 + 1] = ((u64)mapf(bestv2[im]) << 32);
    }
    __syncthreads();
    if (tid < 128) {
        const u64* base = red + tid * 32;
        u64 p1 = base[0];
        u64 s2 = base[1];
#pragma unroll
        for (int t = 1; t < 16; t++) {
            u64 c1 = base[t * 2], c2 = base[t * 2 + 1];
            if (c1 < p1) { s2 = (p1 < s2) ? p1 : s2; p1 = c1; }
            else         { s2 = (c1 < s2) ? c1 : s2; }
            s2 = (c2 < s2) ? c2 : s2;
        }
        int n = mt * 128 + tid;
        cand2[(size_t)n * 4 + kh * 2]     = p1;
        cand2[(size_t)n * 4 + kh * 2 + 1] = s2;
    }
}

__global__ __launch_bounds__(256) void k_select_fb(const u64* __restrict__ cand2,
                                                   const float* __restrict__ A32,
                                                   int* __restrict__ keys,
                                                   int* __restrict__ cnt,
                                                   int* __restrict__ list) {
    int n = blockIdx.x * 256 + threadIdx.x;
    u64 a1 = cand2[(size_t)n * 4 + 0], a2 = cand2[(size_t)n * 4 + 1];
    u64 b1 = cand2[(size_t)n * 4 + 2], b2 = cand2[(size_t)n * 4 + 3];
    u64 m1 = (a1 < b1) ? a1 : b1;
    u64 lo = (a1 < b1) ? b1 : a1;
    u64 m2 = (a2 < b2) ? a2 : b2;
    m2 = (lo < m2) ? lo : m2;

    keys[n] = (int)(unsigned)(m1 & 0xFFFFFFFFull);
    float f1 = unmapf((unsigned)(m1 >> 32));
    float f2 = unmapf((unsigned)(m2 >> 32));
    float W = (A32[n] >= 255.9f) ? 3.4e-5f : 1.8e-5f;
    if (f2 - f1 <= W) {
        int p = atomicAdd(cnt, 1);
        list[p] = n;
    }
}

// ---------------------------------------------------------------------------
// exact np-fp32 emulation for flagged rows (round-3 proven)
// ---------------------------------------------------------------------------
__global__ __launch_bounds__(256) void k_refine(const float* __restrict__ z,
                                                const float* __restrict__ emb,
                                                const float* __restrict__ A32,
                                                const int* __restrict__ list,
                                                const int* __restrict__ cnt,
                                                int* __restrict__ keys) {
    __shared__ __align__(16) float zs[256][8];
    __shared__ float aA[8];
    __shared__ int   ln[8];
    __shared__ u64   wred[4 * 8];

    int tid = threadIdx.x, lane = tid & 63, w = tid >> 6;
    int count = *cnt;
    int ngroups = (count + 7) >> 3;

    for (int g = blockIdx.x; g < ngroups; g += gridDim.x) {
        __syncthreads();
#pragma unroll
        for (int r = 0; r < 8; r++) {
            int row = g * 8 + r;
            int n   = list[(row < count) ? row : 0];
            int b = n >> 11, t = n & 2047;
            zs[tid][r] = z[(size_t)b * (DD * TT) + (size_t)tid * TT + t];
            if (tid == 0) { ln[r] = (row < count) ? n : -1; aA[r] = A32[n]; }
        }
        __syncthreads();

        u64 best[8];
#pragma unroll
        for (int r = 0; r < 8; r++) best[r] = 0xFFFFFFFFFFFFFFFFull;

        float Ar[8];
#pragma unroll
        for (int r = 0; r < 8; r++) Ar[r] = aA[r];

        for (int c = 0; c < 8; c++) {
            int kbase = c * 1024 + tid;
            const float4* e0 = (const float4*)(emb + (size_t)(kbase)       * DD);
            const float4* e1 = (const float4*)(emb + (size_t)(kbase + 256) * DD);
            const float4* e2 = (const float4*)(emb + (size_t)(kbase + 512) * DD);
            const float4* e3 = (const float4*)(emb + (size_t)(kbase + 768) * DD);
            float acc[4][8];
#pragma unroll
            for (int qq = 0; qq < 4; qq++)
#pragma unroll
                for (int r = 0; r < 8; r++) acc[qq][r] = 0.0f;

            for (int d4 = 0; d4 < 64; d4++) {
                float4 v0 = e0[d4], v1 = e1[d4], v2 = e2[d4], v3 = e3[d4];
                const float* p0 = (const float*)&v0;
                const float* p1 = (const float*)&v1;
                const float* p2 = (const float*)&v2;
                const float* p3 = (const float*)&v3;
#pragma unroll
                for (int i = 0; i < 4; i++) {
                    int d = 4 * d4 + i;
                    float4 za = *(const float4*)&zs[d][0];
                    float4 zb2 = *(const float4*)&zs[d][4];
                    const float* zr  = (const float*)&za;
                    const float* zr2 = (const float*)&zb2;
#pragma unroll
                    for (int r = 0; r < 4; r++) {
                        acc[0][r]     = fmaf(zr[r],  p0[i], acc[0][r]);
                        acc[1][r]     = fmaf(zr[r],  p1[i], acc[1][r]);
                        acc[2][r]     = fmaf(zr[r],  p2[i], acc[2][r]);
                        acc[3][r]     = fmaf(zr[r],  p3[i], acc[3][r]);
                        acc[0][r + 4] = fmaf(zr2[r], p0[i], acc[0][r + 4]);
                        acc[1][r + 4] = fmaf(zr2[r], p1[i], acc[1][r + 4]);
                        acc[2][r + 4] = fmaf(zr2[r], p2[i], acc[2][r + 4]);
                        acc[3][r + 4] = fmaf(zr2[r], p3[i], acc[3][r + 4]);
                    }
                }
            }
#pragma unroll
            for (int qq = 0; qq < 4; qq++) {
                int k = kbase + qq * 256;
#pragma unroll
                for (int r = 0; r < 8; r++) {
                    float dk = Ar[r] - 2.0f * acc[qq][r];
                    u64 p = ((u64)mapf(dk) << 32) | (unsigned)k;
                    best[r] = (p < best[r]) ? p : best[r];
                }
            }
        }
#pragma unroll
        for (int r = 0; r < 8; r++) {
            u64 v = best[r];
            for (int off = 32; off; off >>= 1) {
                u64 o = __shfl_down(v, off, 64);
                v = (o < v) ? o : v;
            }
            if (lane == 0) wred[w * 8 + r] = v;
        }
        __syncthreads();
        if (tid < 8) {
            u64 v = wred[tid];
#pragma unroll
            for (int j = 1; j < 4; j++) {
                u64 o = wred[j * 8 + tid];
                v = (o < v) ? o : v;
            }
            int n = ln[tid];
            if (n >= 0) keys[n] = (int)(unsigned)(v & 0xFFFFFFFFull);
        }
        __syncthreads();
    }
}

// ---------------------------------------------------------------------------
// gather quantized, write outputs, loss = 1.25 * mean((q - z)^2)
// ---------------------------------------------------------------------------
__global__ __launch_bounds__(256) void k_out(const float* __restrict__ z,
                                             const float* __restrict__ emb,
                                             const int* __restrict__ keys,
                                             float* __restrict__ out) {
    int tid = threadIdx.x;
    int n   = blockIdx.x * 256 + tid;
    int b   = n >> 11;
    int t   = n & 2047;
    int idx = keys[n];
    out[QQ + 1 + n] = (float)idx;

    const float4* erow = (const float4*)(emb + (size_t)idx * DD);
    const float*  zp   = z   + (size_t)b * (DD * TT) + t;
    float*        op   = out + (size_t)b * (DD * TT) + t;

    float ssd = 0.0f;
#pragma unroll 4
    for (int d4 = 0; d4 < 64; d4++) {
        float4 qv = erow[d4];
        float qa[4] = {qv.x, qv.y, qv.z, qv.w};
#pragma unroll
        for (int r = 0; r < 4; r++) {
            int d = 4 * d4 + r;
            float zv = zp[(size_t)d * TT];
            float df = qa[r] - zv;
            ssd = fmaf(df, df, ssd);
            op[(size_t)d * TT] = qa[r];
        }
    }
    for (int off = 32; off; off >>= 1) ssd += __shfl_down(ssd, off, 64);
    __shared__ float red[4];
    if ((tid & 63) == 0) red[tid >> 6] = ssd;
    __syncthreads();
    if (tid == 0) {
        float tot = red[0] + red[1] + red[2] + red[3];
        atomicAdd(out + QQ, tot * (1.25f / (float)QQ));
    }
}

// ---------------------------------------------------------------------------
extern "C" void kernel_launch(void* const* d_in, const int* in_sizes, int n_in,
                              void* d_out, int out_size, void* d_ws, size_t ws_size,
                              hipStream_t stream) {
    const float* z   = (const float*)d_in[0];   // [16, 256, 2048]
    const float* emb = (const float*)d_in[1];   // [8192, 256]
    float* out = (float*)d_out;

    char* ws = (char*)d_ws;
    // MFMA-path layout (46.6 MB)
    const size_t oZH = 0;
    const size_t oZL = oZH + 16777216;
    const size_t oEH = oZL + 16777216;
    const size_t oEL = oEH + 4194304;
    const size_t oCD = oEL + 4194304;          // cand: 8*32768*2*8 = 4 MB
    const size_t oA3 = oCD + 4194304;
    const size_t oKY = oA3 + 131072;
    const size_t oLS = oKY + 131072;
    const size_t oCN = oLS + 131072;
    const size_t needed = oCN + 64;

    if (ws_size >= needed) {
        unsigned short* zh = (unsigned short*)(ws + oZH);
        unsigned short* zl = (unsigned short*)(ws + oZL);
        unsigned short* eh = (unsigned short*)(ws + oEH);
        unsigned short* el = (unsigned short*)(ws + oEL);
        u64*   cand = (u64*)(ws + oCD);
        float* A32  = (float*)(ws + oA3);
        int*   keys = (int*)(ws + oKY);
        int*   list = (int*)(ws + oLS);
        int*   cnt  = (int*)(ws + oCN);

        k_prepA <<<512,  256, 0, stream>>>(z, A32, cnt, out);
        k_convZ <<<2048, 256, 0, stream>>>(z, zh, zl);
        k_convE <<<1024, 256, 0, stream>>>(emb, eh, el);
        k_gemm  <<<2048, 256, 0, stream>>>(zh, zl, eh, el, cand);
        k_select<<<128,  256, 0, stream>>>(cand, A32, keys, cnt, list);
        k_refine<<<256,  256, 0, stream>>>(z, emb, A32, list, cnt, keys);
        k_out   <<<128,  256, 0, stream>>>(z, emb, keys, out);
    } else {
        // fallback: round-3 proven path (~1.5 MB ws)
        u64*   cand2 = (u64*)ws;                          // 1 MB
        float* A32   = (float*)(ws + 1048576);            // 128 KB
        int*   keys  = (int*)(ws + 1048576 + 131072);
        int*   list  = (int*)(ws + 1048576 + 262144);
        int*   cnt   = (int*)(ws + 1048576 + 393216);

        k_prepA    <<<512,          256, 0, stream>>>(z, A32, cnt, out);
        k_argmin_fb<<<dim3(256, 2), 256, 0, stream>>>(z, emb, cand2);
        k_select_fb<<<128,          256, 0, stream>>>(cand2, A32, keys, cnt, list);
        k_refine   <<<256,          256, 0, stream>>>(z, emb, A32, list, cnt, keys);
        k_out      <<<128,          256, 0, stream>>>(z, emb, keys, out);
    }
}

// Round 5
// 1121.935 us; speedup vs baseline: 2.1827x; 1.1872x over previous
//
#include <hip/hip_runtime.h>
#include <cstdint>

#define BB 16
#define DD 256
#define TT 2048
#define KK 8192
#define NN 32768            // BB*TT
#define QQ 8388608          // BB*DD*TT
typedef unsigned long long u64;

typedef __attribute__((ext_vector_type(8))) short short8;   // 8 bf16 (4 VGPRs)
typedef __attribute__((ext_vector_type(4))) float f32x4;    // MFMA C/D

#define GLOBAL_AS __attribute__((address_space(1)))
#define LDS_AS    __attribute__((address_space(3)))

// async global->LDS, 16 B per lane; LDS dest = wave-uniform base + lane*16
__device__ __forceinline__ void async_copy16(void* l, const void* g) {
    __builtin_amdgcn_global_load_lds((const GLOBAL_AS unsigned int*)g,
                                     (LDS_AS unsigned int*)l, 16, 0, 0);
}

__device__ __forceinline__ unsigned mapf(float f) {
    unsigned u = __float_as_uint(f);
    return (u & 0x80000000u) ? ~u : (u | 0x80000000u);
}
__device__ __forceinline__ float unmapf(unsigned u) {
    return __uint_as_float((u & 0x80000000u) ? (u & 0x7FFFFFFFu) : ~u);
}
__device__ __forceinline__ unsigned bf16_rne(float v) {
    unsigned ui = __float_as_uint(v);
    return (ui + 0x7FFFu + ((ui >> 16) & 1)) >> 16;
}

// ---------------------------------------------------------------------------
// A32[n] = fp32(fp64 sum of z_n^2); zero cnt & loss. grid 512 x 256
// ---------------------------------------------------------------------------
__global__ __launch_bounds__(256) void k_prepA(const float* __restrict__ z,
                                               float* __restrict__ A32,
                                               int* __restrict__ cnt,
                                               float* __restrict__ out) {
    __shared__ double sd[256];
    int tid = threadIdx.x;
    int r = tid & 63;               // row within block (coalesced over t)
    int c = tid >> 6;               // wave -> d quarter
    int n = blockIdx.x * 64 + r;
    if (blockIdx.x == 0 && tid == 0) { *cnt = 0; out[QQ] = 0.0f; }
    int b = n >> 11, t = n & 2047;
    const float* zp = z + (size_t)b * 524288 + t;
    double s = 0.0;
#pragma unroll 8
    for (int i = 0; i < 64; i++) {
        float v = zp[(size_t)(c * 64 + i) * 2048];
        s = fma((double)v, (double)v, s);
    }
    sd[tid] = s;
    __syncthreads();
    if (c == 0) {
        double tot = sd[r] + sd[64 + r] + sd[128 + r] + sd[192 + r];
        A32[n] = (float)tot;
    }
}

// ---------------------------------------------------------------------------
// z [b][d][t] fp32 -> zh/zl [n][d] bf16 hi/lo, 16B stores. grid 2048 x 256
// ---------------------------------------------------------------------------
__global__ __launch_bounds__(256) void k_convZ(const float* __restrict__ z,
                                               unsigned short* __restrict__ zh,
                                               unsigned short* __restrict__ zl) {
    __shared__ float sm[64][65];
    int tid = threadIdx.x;
    int bid = blockIdx.x;
    int b  = bid >> 7;
    int dt = (bid >> 5) & 3;
    int tt = bid & 31;
    const float* zp = z + (size_t)b * 524288 + (size_t)dt * 131072 + tt * 64;
#pragma unroll
    for (int i = 0; i < 16; i++) {
        int idx = tid + 256 * i;
        int d = idx >> 6, t = idx & 63;
        sm[d][t] = zp[(size_t)d * 2048 + t];
    }
    __syncthreads();
    int d0 = (tid & 7) * 8;
#pragma unroll
    for (int i = 0; i < 2; i++) {
        int t = (tid >> 3) + 32 * i;
        size_t o = ((size_t)(b * 2048 + tt * 64 + t)) * 256 + dt * 64 + d0;
        short8 hv, lv;
#pragma unroll
        for (int j = 0; j < 8; j++) {
            float v = sm[d0 + j][t];
            unsigned hb = bf16_rne(v);
            float hf = __uint_as_float(hb << 16);
            unsigned lb = bf16_rne(v - hf);
            hv[j] = (short)hb;
            lv[j] = (short)lb;
        }
        *(short8*)(zh + o) = hv;
        *(short8*)(zl + o) = lv;
    }
}

// ---------------------------------------------------------------------------
// emb [k][d] fp32 -> eh/el bf16 hi/lo. grid 1024 x 256
// ---------------------------------------------------------------------------
__global__ __launch_bounds__(256) void k_convE(const float* __restrict__ emb,
                                               unsigned short* __restrict__ eh,
                                               unsigned short* __restrict__ el) {
    int base = (blockIdx.x * 256 + threadIdx.x) * 8;
    float4 v0 = *(const float4*)(emb + base);
    float4 v1 = *(const float4*)(emb + base + 4);
    float vv[8] = {v0.x, v0.y, v0.z, v0.w, v1.x, v1.y, v1.z, v1.w};
    short8 hv, lv;
#pragma unroll
    for (int i = 0; i < 8; i++) {
        unsigned hb = bf16_rne(vv[i]);
        float hf = __uint_as_float(hb << 16);
        unsigned lb = bf16_rne(vv[i] - hf);
        hv[i] = (short)hb;
        lv[i] = (short)lb;
    }
    *(short8*)(eh + base) = hv;
    *(short8*)(el + base) = lv;
}

// ---------------------------------------------------------------------------
// MFMA distance GEMM v2: score = -2*(zh.eh + zh.el + zl.eh)
// Fused 3 phases per staging; fragment-major LDS (conflict-free lane*16 reads).
// Block: 128 rows x 1024 codes (8 slabs of 128). grid 2048 (mt=bid&255, ng=bid>>8).
// ---------------------------------------------------------------------------
__global__ __launch_bounds__(256, 3) void k_gemm(const unsigned short* __restrict__ zh,
                                                 const unsigned short* __restrict__ zl,
                                                 const unsigned short* __restrict__ eh,
                                                 const unsigned short* __restrict__ el,
                                                 u64* __restrict__ cand) {
    // fragment-major: tile t (16 rows x 32 k) occupies [t*512, t*512+512) shorts;
    // slot l (16B) within a tile holds (row = l&15, k-chunk = l>>4)
    __shared__ __align__(16) unsigned short Azh[4096];   // 8 KB each
    __shared__ __align__(16) unsigned short Azl[4096];
    __shared__ __align__(16) unsigned short Beh[4096];
    __shared__ __align__(16) unsigned short Bel[4096];
    __shared__ u64 rtop[256];

    int tid  = threadIdx.x;
    int w    = tid >> 6;
    int lane = tid & 63;
    int lm   = lane & 15;
    int q    = lane >> 4;

    int bid = blockIdx.x;
    int mt  = bid & 255;
    int ng  = bid >> 8;

    // staging: lane fetches global (row = lane&15 within tile, chunk = lane>>4)
    int srow   = lane & 15;
    int schunk = lane >> 4;
    int t0 = 2 * w, t1 = 2 * w + 1;               // this wave's tiles
    size_t ga0 = (size_t)(t0 * 16 + srow) * 256;  // + koff later
    size_t ga1 = (size_t)(t1 * 16 + srow) * 256;

    const unsigned short* Ah = zh + (size_t)mt * 32768;
    const unsigned short* Al = zl + (size_t)mt * 32768;

    u64 top1[2][4], top2[2][4];
#pragma unroll
    for (int mi = 0; mi < 2; mi++)
#pragma unroll
        for (int r = 0; r < 4; r++) { top1[mi][r] = ~0ull; top2[mi][r] = ~0ull; }

    for (int ns = 0; ns < 8; ns++) {
        int n0 = ng * 1024 + ns * 128;
        const unsigned short* Bh = eh + (size_t)n0 * 256;
        const unsigned short* Bl = el + (size_t)n0 * 256;

        f32x4 acc[2][8];
#pragma unroll
        for (int mi = 0; mi < 2; mi++)
#pragma unroll
            for (int ni = 0; ni < 8; ni++) acc[mi][ni] = (f32x4){0.f, 0.f, 0.f, 0.f};

        for (int kc = 0; kc < 8; kc++) {
            int koff = kc * 32 + schunk * 8;
            __syncthreads();
            async_copy16(&Azh[t0 * 512], Ah + ga0 + koff);
            async_copy16(&Azh[t1 * 512], Ah + ga1 + koff);
            async_copy16(&Azl[t0 * 512], Al + ga0 + koff);
            async_copy16(&Azl[t1 * 512], Al + ga1 + koff);
            async_copy16(&Beh[t0 * 512], Bh + ga0 + koff);
            async_copy16(&Beh[t1 * 512], Bh + ga1 + koff);
            async_copy16(&Bel[t0 * 512], Bl + ga0 + koff);
            async_copy16(&Bel[t1 * 512], Bl + ga1 + koff);
            __syncthreads();

            short8 a0h = *(const short8*)&Azh[t0 * 512 + lane * 8];
            short8 a1h = *(const short8*)&Azh[t1 * 512 + lane * 8];
            short8 a0l = *(const short8*)&Azl[t0 * 512 + lane * 8];
            short8 a1l = *(const short8*)&Azl[t1 * 512 + lane * 8];
#pragma unroll
            for (int ni = 0; ni < 8; ni++) {
                short8 bh = *(const short8*)&Beh[ni * 512 + lane * 8];
                short8 bl = *(const short8*)&Bel[ni * 512 + lane * 8];
                acc[0][ni] = __builtin_amdgcn_mfma_f32_16x16x32_bf16(a0h, bh, acc[0][ni], 0, 0, 0);
                acc[1][ni] = __builtin_amdgcn_mfma_f32_16x16x32_bf16(a1h, bh, acc[1][ni], 0, 0, 0);
                acc[0][ni] = __builtin_amdgcn_mfma_f32_16x16x32_bf16(a0l, bh, acc[0][ni], 0, 0, 0);
                acc[1][ni] = __builtin_amdgcn_mfma_f32_16x16x32_bf16(a1l, bh, acc[1][ni], 0, 0, 0);
                acc[0][ni] = __builtin_amdgcn_mfma_f32_16x16x32_bf16(a0h, bl, acc[0][ni], 0, 0, 0);
                acc[1][ni] = __builtin_amdgcn_mfma_f32_16x16x32_bf16(a1h, bl, acc[1][ni], 0, 0, 0);
            }
        }
        // per-lane top-2 update in registers (codes ascending: ns, then ni)
#pragma unroll
        for (int mi = 0; mi < 2; mi++)
#pragma unroll
            for (int reg = 0; reg < 4; reg++) {
#pragma unroll
                for (int ni = 0; ni < 8; ni++) {
                    float sc = -2.0f * acc[mi][ni][reg];
                    u64 pk = ((u64)mapf(sc) << 32) | (unsigned)(n0 + ni * 16 + lm);
                    if (pk < top1[mi][reg]) { top2[mi][reg] = top1[mi][reg]; top1[mi][reg] = pk; }
                    else if (pk < top2[mi][reg]) { top2[mi][reg] = pk; }
                }
            }
    }

    // butterfly across the 16 lm-lanes (bits 0..3 of lane)
#pragma unroll
    for (int mi = 0; mi < 2; mi++)
#pragma unroll
        for (int reg = 0; reg < 4; reg++) {
            u64 p1 = top1[mi][reg], p2 = top2[mi][reg];
#pragma unroll
            for (int msk = 1; msk <= 8; msk <<= 1) {
                u64 q1 = __shfl_xor(p1, msk, 64);
                u64 q2 = __shfl_xor(p2, msk, 64);
                u64 n1 = (p1 < q1) ? p1 : q1;
                u64 hi = (p1 < q1) ? q1 : p1;
                u64 n2 = (q2 < p2) ? q2 : p2;
                n2 = (hi < n2) ? hi : n2;
                p1 = n1; p2 = n2;
            }
            if (lm == 0) {
                int m = w * 32 + mi * 16 + q * 4 + reg;   // exclusive owner row
                rtop[m * 2]     = p1;
                rtop[m * 2 + 1] = p2;
            }
        }
    __syncthreads();
    if (tid < 128) {
        size_t o = ((size_t)ng * 32768 + (size_t)mt * 128 + tid) * 2;
        cand[o]     = rtop[tid * 2];
        cand[o + 1] = rtop[tid * 2 + 1];
    }
}

// ---------------------------------------------------------------------------
// select (MFMA path): merge 8 (top1,top2) pairs; commit or flag. grid 128
// ---------------------------------------------------------------------------
__global__ __launch_bounds__(256) void k_select(const u64* __restrict__ cand,
                                                const float* __restrict__ A32,
                                                int* __restrict__ keys,
                                                int* __restrict__ cnt,
                                                int* __restrict__ list) {
    int n = blockIdx.x * 256 + threadIdx.x;
    u64 m1 = cand[(size_t)n * 2];
    u64 m2 = cand[(size_t)n * 2 + 1];
#pragma unroll
    for (int j = 1; j < 8; j++) {
        u64 c1 = cand[((size_t)j * 32768 + n) * 2];
        u64 c2 = cand[((size_t)j * 32768 + n) * 2 + 1];
        if (c1 < m1) { m2 = (m1 < m2) ? m1 : m2; m1 = c1; }
        else         { m2 = (c1 < m2) ? c1 : m2; }
        m2 = (c2 < m2) ? c2 : m2;
    }
    keys[n] = (int)(unsigned)(m1 & 0xFFFFFFFFull);
    float f1 = unmapf((unsigned)(m1 >> 32));
    float f2 = unmapf((unsigned)(m2 >> 32));
    float W = ((A32[n] >= 255.9f) ? 3.4e-5f : 1.8e-5f) + 4e-6f;  // + 2*eps(bf16x3)
    if (f2 - f1 <= W) {
        int p = atomicAdd(cnt, 1);
        list[p] = n;
    }
}

// ---------------------------------------------------------------------------
// FALLBACK path (round-3 proven): fp32 VALU GEMM argmin + its select
// ---------------------------------------------------------------------------
__global__ __launch_bounds__(256) void k_argmin_fb(const float* __restrict__ z,
                                                   const float* __restrict__ emb,
                                                   u64* __restrict__ cand2) {
    __shared__ __align__(16) float smem[8192];
    float* As = smem;
    float* Bs = smem + 4096;

    int tid = threadIdx.x;
    int tx  = tid & 15;
    int ty  = tid >> 4;
    int mt  = blockIdx.x;
    int kh  = blockIdx.y;

    int bimg = mt >> 4;
    int t0   = (mt & 15) << 7;
    const float* zb = z + (size_t)bimg * (DD * TT) + t0;

    float bestv[8], bestv2[8];
    int   besti[8];
#pragma unroll
    for (int i = 0; i < 8; i++) { bestv[i] = 3.4e38f; bestv2[i] = 3.4e38f; besti[i] = 0; }

    int qa = tid & 31, ra = tid >> 5;
    int jb = tid >> 3, db = tid & 7;
    int swz_t = (tx & 7) << 2;

    for (int kc = 0; kc < 32; kc++) {
        int k0 = kh * 4096 + kc * 128;
        float acc[8][8];
#pragma unroll
        for (int i = 0; i < 8; i++)
#pragma unroll
            for (int j = 0; j < 8; j++) acc[i][j] = 0.0f;

        for (int dc = 0; dc < 8; dc++) {
            int d0 = dc * 32;
            __syncthreads();
#pragma unroll
            for (int s = 0; s < 4; s++) {
                int d = ra + 8 * s;
                float4 v = *(const float4*)(zb + (size_t)(d0 + d) * TT + 4 * qa);
                *(float4*)(As + d * 128 + 4 * qa) = v;
            }
#pragma unroll
            for (int s = 0; s < 4; s++) {
                int row = jb + 32 * s;
                float4 v = *(const float4*)(emb + (size_t)(k0 + row) * DD + d0 + 4 * db);
                int col  = (4 * db) ^ ((row & 7) << 2);
                *(float4*)(Bs + row * 32 + col) = v;
            }
            __syncthreads();
#pragma unroll
            for (int g = 0; g < 8; g++) {
                float4 bf[8];
#pragma unroll
                for (int in = 0; in < 8; in++) {
                    int nn = in * 16 + tx;
                    bf[in] = *(const float4*)(Bs + nn * 32 + ((4 * g) ^ swz_t));
                }
#pragma unroll
                for (int j = 0; j < 4; j++) {
                    int d = 4 * g + j;
                    float4 a0 = *(const float4*)(As + d * 128 + ty * 8);
                    float4 a1 = *(const float4*)(As + d * 128 + ty * 8 + 4);
                    float av[8] = {a0.x, a0.y, a0.z, a0.w, a1.x, a1.y, a1.z, a1.w};
#pragma unroll
                    for (int im = 0; im < 8; im++) {
#pragma unroll
                        for (int in = 0; in < 8; in++) {
                            const float* bfp = (const float*)&bf[in];
                            acc[im][in] = fmaf(av[im], bfp[j], acc[im][in]);
                        }
                    }
                }
            }
        }
#pragma unroll
        for (int in = 0; in < 8; in++) {
            int k = k0 + in * 16 + tx;
#pragma unroll
            for (int im = 0; im < 8; im++) {
                float s = -2.0f * acc[im][in];
                if (s < bestv[im]) { bestv2[im] = bestv[im]; bestv[im] = s; besti[im] = k; }
                else if (s < bestv2[im]) { bestv2[im] = s; }
            }
        }
    }

    __syncthreads();
    u64* red = (u64*)smem;
#pragma unroll
    for (int im = 0; im < 8; im++) {
        int r = ty * 8 + im;
        red[r * 32 + tx * 2 + 0] = ((u64)mapf(bestv[im]) << 32) | (unsigned)besti[im];
        red[r * 32 + tx * 2 + 1] = ((u64)mapf(bestv2[im]) << 32);
    }
    __syncthreads();
    if (tid < 128) {
        const u64* base = red + tid * 32;
        u64 p1 = base[0];
        u64 s2 = base[1];
#pragma unroll
        for (int t = 1; t < 16; t++) {
            u64 c1 = base[t * 2], c2 = base[t * 2 + 1];
            if (c1 < p1) { s2 = (p1 < s2) ? p1 : s2; p1 = c1; }
            else         { s2 = (c1 < s2) ? c1 : s2; }
            s2 = (c2 < s2) ? c2 : s2;
        }
        int n = mt * 128 + tid;
        cand2[(size_t)n * 4 + kh * 2]     = p1;
        cand2[(size_t)n * 4 + kh * 2 + 1] = s2;
    }
}

__global__ __launch_bounds__(256) void k_select_fb(const u64* __restrict__ cand2,
                                                   const float* __restrict__ A32,
                                                   int* __restrict__ keys,
                                                   int* __restrict__ cnt,
                                                   int* __restrict__ list) {
    int n = blockIdx.x * 256 + threadIdx.x;
    u64 a1 = cand2[(size_t)n * 4 + 0], a2 = cand2[(size_t)n * 4 + 1];
    u64 b1 = cand2[(size_t)n * 4 + 2], b2 = cand2[(size_t)n * 4 + 3];
    u64 m1 = (a1 < b1) ? a1 : b1;
    u64 lo = (a1 < b1) ? b1 : a1;
    u64 m2 = (a2 < b2) ? a2 : b2;
    m2 = (lo < m2) ? lo : m2;

    keys[n] = (int)(unsigned)(m1 & 0xFFFFFFFFull);
    float f1 = unmapf((unsigned)(m1 >> 32));
    float f2 = unmapf((unsigned)(m2 >> 32));
    float W = (A32[n] >= 255.9f) ? 3.4e-5f : 1.8e-5f;
    if (f2 - f1 <= W) {
        int p = atomicAdd(cnt, 1);
        list[p] = n;
    }
}

// ---------------------------------------------------------------------------
// exact np-fp32 emulation for flagged rows (round-3 proven). grid 512
// ---------------------------------------------------------------------------
__global__ __launch_bounds__(256) void k_refine(const float* __restrict__ z,
                                                const float* __restrict__ emb,
                                                const float* __restrict__ A32,
                                                const int* __restrict__ list,
                                                const int* __restrict__ cnt,
                                                int* __restrict__ keys) {
    __shared__ __align__(16) float zs[256][8];
    __shared__ float aA[8];
    __shared__ int   ln[8];
    __shared__ u64   wred[4 * 8];

    int tid = threadIdx.x, lane = tid & 63, w = tid >> 6;
    int count = *cnt;
    int ngroups = (count + 7) >> 3;

    for (int g = blockIdx.x; g < ngroups; g += gridDim.x) {
        __syncthreads();
#pragma unroll
        for (int r = 0; r < 8; r++) {
            int row = g * 8 + r;
            int n   = list[(row < count) ? row : 0];
            int b = n >> 11, t = n & 2047;
            zs[tid][r] = z[(size_t)b * (DD * TT) + (size_t)tid * TT + t];
            if (tid == 0) { ln[r] = (row < count) ? n : -1; aA[r] = A32[n]; }
        }
        __syncthreads();

        u64 best[8];
#pragma unroll
        for (int r = 0; r < 8; r++) best[r] = 0xFFFFFFFFFFFFFFFFull;

        float Ar[8];
#pragma unroll
        for (int r = 0; r < 8; r++) Ar[r] = aA[r];

        for (int c = 0; c < 8; c++) {
            int kbase = c * 1024 + tid;
            const float4* e0 = (const float4*)(emb + (size_t)(kbase)       * DD);
            const float4* e1 = (const float4*)(emb + (size_t)(kbase + 256) * DD);
            const float4* e2 = (const float4*)(emb + (size_t)(kbase + 512) * DD);
            const float4* e3 = (const float4*)(emb + (size_t)(kbase + 768) * DD);
            float acc[4][8];
#pragma unroll
            for (int qq = 0; qq < 4; qq++)
#pragma unroll
                for (int r = 0; r < 8; r++) acc[qq][r] = 0.0f;

            for (int d4 = 0; d4 < 64; d4++) {
                float4 v0 = e0[d4], v1 = e1[d4], v2 = e2[d4], v3 = e3[d4];
                const float* p0 = (const float*)&v0;
                const float* p1 = (const float*)&v1;
                const float* p2 = (const float*)&v2;
                const float* p3 = (const float*)&v3;
#pragma unroll
                for (int i = 0; i < 4; i++) {
                    int d = 4 * d4 + i;
                    float4 za = *(const float4*)&zs[d][0];
                    float4 zb2 = *(const float4*)&zs[d][4];
                    const float* zr  = (const float*)&za;
                    const float* zr2 = (const float*)&zb2;
#pragma unroll
                    for (int r = 0; r < 4; r++) {
                        acc[0][r]     = fmaf(zr[r],  p0[i], acc[0][r]);
                        acc[1][r]     = fmaf(zr[r],  p1[i], acc[1][r]);
                        acc[2][r]     = fmaf(zr[r],  p2[i], acc[2][r]);
                        acc[3][r]     = fmaf(zr[r],  p3[i], acc[3][r]);
                        acc[0][r + 4] = fmaf(zr2[r], p0[i], acc[0][r + 4]);
                        acc[1][r + 4] = fmaf(zr2[r], p1[i], acc[1][r + 4]);
                        acc[2][r + 4] = fmaf(zr2[r], p2[i], acc[2][r + 4]);
                        acc[3][r + 4] = fmaf(zr2[r], p3[i], acc[3][r + 4]);
                    }
                }
            }
#pragma unroll
            for (int qq = 0; qq < 4; qq++) {
                int k = kbase + qq * 256;
#pragma unroll
                for (int r = 0; r < 8; r++) {
                    float dk = Ar[r] - 2.0f * acc[qq][r];
                    u64 p = ((u64)mapf(dk) << 32) | (unsigned)k;
                    best[r] = (p < best[r]) ? p : best[r];
                }
            }
        }
#pragma unroll
        for (int r = 0; r < 8; r++) {
            u64 v = best[r];
            for (int off = 32; off; off >>= 1) {
                u64 o = __shfl_down(v, off, 64);
                v = (o < v) ? o : v;
            }
            if (lane == 0) wred[w * 8 + r] = v;
        }
        __syncthreads();
        if (tid < 8) {
            u64 v = wred[tid];
#pragma unroll
            for (int j = 1; j < 4; j++) {
                u64 o = wred[j * 8 + tid];
                v = (o < v) ? o : v;
            }
            int n = ln[tid];
            if (n >= 0) keys[n] = (int)(unsigned)(v & 0xFFFFFFFFull);
        }
        __syncthreads();
    }
}

// ---------------------------------------------------------------------------
// gather quantized, write outputs, loss = 1.25 * mean((q - z)^2)
// ---------------------------------------------------------------------------
__global__ __launch_bounds__(256) void k_out(const float* __restrict__ z,
                                             const float* __restrict__ emb,
                                             const int* __restrict__ keys,
                                             float* __restrict__ out) {
    int tid = threadIdx.x;
    int n   = blockIdx.x * 256 + tid;
    int b   = n >> 11;
    int t   = n & 2047;
    int idx = keys[n];
    out[QQ + 1 + n] = (float)idx;

    const float4* erow = (const float4*)(emb + (size_t)idx * DD);
    const float*  zp   = z   + (size_t)b * (DD * TT) + t;
    float*        op   = out + (size_t)b * (DD * TT) + t;

    float ssd = 0.0f;
#pragma unroll 4
    for (int d4 = 0; d4 < 64; d4++) {
        float4 qv = erow[d4];
        float qa[4] = {qv.x, qv.y, qv.z, qv.w};
#pragma unroll
        for (int r = 0; r < 4; r++) {
            int d = 4 * d4 + r;
            float zv = zp[(size_t)d * TT];
            float df = qa[r] - zv;
            ssd = fmaf(df, df, ssd);
            op[(size_t)d * TT] = qa[r];
        }
    }
    for (int off = 32; off; off >>= 1) ssd += __shfl_down(ssd, off, 64);
    __shared__ float red[4];
    if ((tid & 63) == 0) red[tid >> 6] = ssd;
    __syncthreads();
    if (tid == 0) {
        float tot = red[0] + red[1] + red[2] + red[3];
        atomicAdd(out + QQ, tot * (1.25f / (float)QQ));
    }
}

// ---------------------------------------------------------------------------
extern "C" void kernel_launch(void* const* d_in, const int* in_sizes, int n_in,
                              void* d_out, int out_size, void* d_ws, size_t ws_size,
                              hipStream_t stream) {
    const float* z   = (const float*)d_in[0];   // [16, 256, 2048]
    const float* emb = (const float*)d_in[1];   // [8192, 256]
    float* out = (float*)d_out;

    char* ws = (char*)d_ws;
    const size_t oZH = 0;
    const size_t oZL = oZH + 16777216;
    const size_t oEH = oZL + 16777216;
    const size_t oEL = oEH + 4194304;
    const size_t oCD = oEL + 4194304;          // cand: 8*32768*2*8 = 4 MB
    const size_t oA3 = oCD + 4194304;
    const size_t oKY = oA3 + 131072;
    const size_t oLS = oKY + 131072;
    const size_t oCN = oLS + 131072;
    const size_t needed = oCN + 64;

    if (ws_size >= needed) {
        unsigned short* zh = (unsigned short*)(ws + oZH);
        unsigned short* zl = (unsigned short*)(ws + oZL);
        unsigned short* eh = (unsigned short*)(ws + oEH);
        unsigned short* el = (unsigned short*)(ws + oEL);
        u64*   cand = (u64*)(ws + oCD);
        float* A32  = (float*)(ws + oA3);
        int*   keys = (int*)(ws + oKY);
        int*   list = (int*)(ws + oLS);
        int*   cnt  = (int*)(ws + oCN);

        k_prepA <<<512,  256, 0, stream>>>(z, A32, cnt, out);
        k_convZ <<<2048, 256, 0, stream>>>(z, zh, zl);
        k_convE <<<1024, 256, 0, stream>>>(emb, eh, el);
        k_gemm  <<<2048, 256, 0, stream>>>(zh, zl, eh, el, cand);
        k_select<<<128,  256, 0, stream>>>(cand, A32, keys, cnt, list);
        k_refine<<<512,  256, 0, stream>>>(z, emb, A32, list, cnt, keys);
        k_out   <<<128,  256, 0, stream>>>(z, emb, keys, out);
    } else {
        // fallback: round-3 proven path (~1.5 MB ws)
        u64*   cand2 = (u64*)ws;                          // 1 MB
        float* A32   = (float*)(ws + 1048576);            // 128 KB
        int*   keys  = (int*)(ws + 1048576 + 131072);
        int*   list  = (int*)(ws + 1048576 + 262144);
        int*   cnt   = (int*)(ws + 1048576 + 393216);

        k_prepA    <<<512,          256, 0, stream>>>(z, A32, cnt, out);
        k_argmin_fb<<<dim3(256, 2), 256, 0, stream>>>(z, emb, cand2);
        k_select_fb<<<128,          256, 0, stream>>>(cand2, A32, keys, cnt, list);
        k_refine   <<<512,          256, 0, stream>>>(z, emb, A32, list, cnt, keys);
        k_out      <<<128,          256, 0, stream>>>(z, emb, keys, out);
    }
}